// Round 11
// baseline (142.659 us; speedup 1.0000x reference)
//
#include <hip/hip_runtime.h>
#include <math.h>

#define BB   4
#define HH   96
#define WW   96
#define HW   (HH * WW)          // 9216
#define CIN  64
#define COUT 64
#define C2B  160                // bf16 concat channels padded 130 -> 160
#define NROW (BB * HW)          // 36864
#define ZROW NROW               // all-zero row for invalid conv taps
#define NSTRIP (NROW / 16)      // 2304 strips of 16 positions = fused grid
#define BPX3 (NSTRIP / 8)       // 288 fused blocks per XCD
#define NA   (9 * 32 * C2B)     // wa2 elements (46080)
#define NW   (9 * 64 * 64)      // wb2 elements (36864)
#define PXB2 (NROW / 32)        // 1152 prep X-blocks (64 rows, half channels)
#define PWBLK 324               // weight blocks covering NA+NW elements
#define TS   49                 // prep LDS tile stride (dwords), conflict-free
#define RS   20                 // reduce-buffer stride (floats): 16B aligned

typedef short v8s __attribute__((ext_vector_type(8)));   // 8 bf16 = 4 VGPRs
typedef float v4f __attribute__((ext_vector_type(4)));

__device__ __forceinline__ unsigned short f2bf(float f) {
    unsigned u = __float_as_uint(f);
    return (unsigned short)((u + 0x7FFFu + ((u >> 16) & 1u)) >> 16);  // RTN-even
}
__device__ __forceinline__ unsigned pack2(float a, float b) {
    return (unsigned)f2bf(a) | ((unsigned)f2bf(b) << 16);
}
// bilinear-combine one packed-bf16-pair dword from each of 4 corners
__device__ __forceinline__ unsigned bil2(unsigned a, unsigned b, unsigned c,
                                         unsigned d, float w00, float w01,
                                         float w10, float w11) {
    float lo = w00 * __uint_as_float(a << 16) + w01 * __uint_as_float(b << 16)
             + w10 * __uint_as_float(c << 16) + w11 * __uint_as_float(d << 16);
    float hi = w00 * __uint_as_float(a & 0xffff0000u)
             + w01 * __uint_as_float(b & 0xffff0000u)
             + w10 * __uint_as_float(c & 0xffff0000u)
             + w11 * __uint_as_float(d & 0xffff0000u);
    return pack2(lo, hi);
}

// ---------------------------------------------------------------------------
// Prep (unchanged from R10): Xt tiles split by channel-half + weight
// transposes + zero row.
// ---------------------------------------------------------------------------
__global__ __launch_bounds__(256) void prep_kernel(
    const float* __restrict__ fi, const float* __restrict__ fj,
    const float* __restrict__ fl, const float* __restrict__ w_off,
    const float* __restrict__ w_mod, const float* __restrict__ w_reg,
    unsigned short* __restrict__ xt, unsigned short* __restrict__ wa2,
    unsigned short* __restrict__ wb2)
{
    int blk = blockIdx.x;
    if (blk < PXB2) {
        __shared__ __align__(16) unsigned tile[64 * TS];   // 12.5 KB
        int tid = threadIdx.x;
        int p = tid & 63, cg = tid >> 6;    // position, channel-group 0..3
        int u = blk >> 1, half = blk & 1;
        int r0 = u * 64;
        int b = r0 / HW;                    // 64-row strip never straddles b
        int hw = r0 - b * HW + p;
        uint4* dst = (uint4*)(xt + (size_t)r0 * C2B);      // 20 quads per row
        if (half == 0) {                    // fi -> dwords 0..31
            const float* pi = fi + (size_t)b * CIN * HW + hw;
#pragma unroll
            for (int d = 0; d < 8; ++d) {
                int c = cg * 16 + 2 * d;
                tile[p * TS + cg * 8 + d] =
                    pack2(pi[(size_t)c * HW], pi[(size_t)(c + 1) * HW]);
            }
            __syncthreads();
#pragma unroll
            for (int i = 0; i < 2; ++i) {   // 512 quads: 8 per row
                int gq = i * 256 + tid;
                int rl = gq >> 3, c4 = gq & 7;
                const unsigned* s = &tile[rl * TS + c4 * 4];
                uint4 v = {s[0], s[1], s[2], s[3]};
                dst[rl * 20 + c4] = v;
            }
        } else {                            // fj+flow+pad -> dwords 32..79
            const float* pj = fj + (size_t)b * CIN * HW + hw;
#pragma unroll
            for (int d = 0; d < 8; ++d) {
                int c = cg * 16 + 2 * d;
                tile[p * TS + cg * 8 + d] =
                    pack2(pj[(size_t)c * HW], pj[(size_t)(c + 1) * HW]);
            }
            if (cg == 0) {
                const float* pf = fl + (size_t)b * 2 * HW + hw;
                tile[p * TS + 32] = pack2(pf[0], pf[HW]);
#pragma unroll
                for (int i = 33; i < 48; ++i) tile[p * TS + i] = 0u;
            }
            __syncthreads();
#pragma unroll
            for (int i = 0; i < 3; ++i) {   // 768 quads: 12 per row
                int gq = i * 256 + tid;
                int rl = gq / 12, c4 = gq - rl * 12;
                const unsigned* s = &tile[rl * TS + c4 * 4];
                uint4 v = {s[0], s[1], s[2], s[3]};
                dst[rl * 20 + 8 + c4] = v;
            }
        }
    } else if (blk < PXB2 + PWBLK) {
        int e = (blk - PXB2) * 256 + threadIdx.x;
        if (e < NA) {
            int c  = e % C2B;
            int oc = (e / C2B) % 32;
            int t  = e / (C2B * 32);
            float v = 0.0f;
            if (oc < 27 && c < 130) {
                if (oc < 18) v = w_off[((size_t)oc * 130 + c) * 9 + t];
                else         v = w_mod[((size_t)(oc - 18) * 130 + c) * 9 + t];
            }
            wa2[e] = f2bf(v);
        } else {
            int e2 = e - NA;
            if (e2 < NW) {
                int c = e2 % 64;
                int o = (e2 / 64) % 64;
                int k = e2 / 4096;
                wb2[e2] = f2bf(w_reg[((size_t)o * 64 + c) * 9 + k]);
            }
        }
    } else {
        if (threadIdx.x < 20) {             // zero row, 20 dwordx4
            uint4 z = {0u, 0u, 0u, 0u};
            ((uint4*)(xt + (size_t)ZROW * C2B))[threadIdx.x] = z;
        }
    }
}

// ---------------------------------------------------------------------------
// Fused conv + deformable conv, 4-way K-split, ONE strip per block.
// Block = 4 waves; wave w handles taps {2w, 2w+1} (+tap 8 for w=3) of BOTH
// phases. Grid 2304 blocks -> 9216 waves (9 blocks/CU, ~28 waves/CU
// co-resident at 22.3 KB LDS) vs R10's 4.5 waves/SIMD grid ceiling.
//  Phase 1 (conv, M=16 x N=32): partials; waves 1-3 publish to red[],
//    wave 0 reduces + bias/2*sigmoid -> lraw[16][28].
//  Phase 2 (deform, M=16 x N=64): offsets from lraw; register-direct
//    bilinear gathers into MFMA A-fragments; all waves publish 16 floats to
//    red[]; wave w reduces + stores n-tile w (outputs w*16..w*16+15).
// 3 barriers total.
// ---------------------------------------------------------------------------
__global__ __launch_bounds__(256) void fused_kernel(
    const unsigned short* __restrict__ xt,
    const unsigned short* __restrict__ wa2,
    const unsigned short* __restrict__ wb2,
    const float* __restrict__ b_off, const float* __restrict__ b_mod,
    float* __restrict__ out)
{
    __shared__ float lraw[16 * 28];                   // 1.8 KB offsets/mods
    __shared__ __align__(16) float red[4][64 * RS];   // 20.5 KB partials

    int l = threadIdx.x & 63;
    int wid = __builtin_amdgcn_readfirstlane(threadIdx.x >> 6);
    int m = l & 15, g = l >> 4;
    int strip = (blockIdx.x & 7) * BPX3 + (blockIdx.x >> 3);  // XCD-contiguous
    int b = strip / (HW / 16);              // wave-uniform
    int hw0 = (strip - b * (HW / 16)) * 16;
    int hw = hw0 + m;
    int x = hw % WW, y = hw / WW;
    int t0 = wid * 2;
    int t1 = (wid == 3) ? 9 : (wid * 2 + 2);

    // ---- Phase 1: conv partials over my taps ----
    v4f acc0 = {0.f, 0.f, 0.f, 0.f};
    v4f acc1 = {0.f, 0.f, 0.f, 0.f};
    for (int t = t0; t < t1; ++t) {
        int ty = t / 3, tx = t - 3 * ty;
        int yy = y + ty - 1, xx = x + tx - 1;
        bool ok = ((unsigned)yy < HH) && ((unsigned)xx < WW);
        int row = ok ? (b * HW + yy * WW + xx) : ZROW;
        const unsigned short* ar = xt + (size_t)row * C2B + g * 8;
        const unsigned short* w0 = wa2 + ((size_t)(t * 32 + m)) * C2B + g * 8;
        const unsigned short* w1 = w0 + 16 * C2B;
#pragma unroll
        for (int ks = 0; ks < 5; ++ks) {
            v8s a  = *(const v8s*)(ar + ks * 32);
            v8s b0 = *(const v8s*)(w0 + ks * 32);
            v8s b1 = *(const v8s*)(w1 + ks * 32);
            acc0 = __builtin_amdgcn_mfma_f32_16x16x32_bf16(a, b0, acc0, 0, 0, 0);
            acc1 = __builtin_amdgcn_mfma_f32_16x16x32_bf16(a, b1, acc1, 0, 0, 0);
        }
    }

    if (wid != 0) {                         // publish partials
        float* rb = &red[wid][l * RS];
        *(v4f*)(rb + 0) = acc0;
        *(v4f*)(rb + 4) = acc1;
    }
    __syncthreads();                        // barrier A
    if (wid == 0) {                         // reduce + epilogue -> lraw
#pragma unroll
        for (int sw = 1; sw < 4; ++sw) {
            const float* rb = &red[sw][l * RS];
            acc0 += *(const v4f*)(rb + 0);
            acc1 += *(const v4f*)(rb + 4);
        }
        float v0[4] = {acc0.x, acc0.y, acc0.z, acc0.w};
        float v1[4] = {acc1.x, acc1.y, acc1.z, acc1.w};
        float bo0 = b_off[m];
        int oc1 = 16 + m;
#pragma unroll
        for (int r = 0; r < 4; ++r)
            lraw[(g * 4 + r) * 28 + m] = v0[r] + bo0;
        if (oc1 < 18) {
            float bo1 = b_off[oc1];
#pragma unroll
            for (int r = 0; r < 4; ++r)
                lraw[(g * 4 + r) * 28 + oc1] = v1[r] + bo1;
        } else if (oc1 < 27) {
            float bm = b_mod[oc1 - 18];
#pragma unroll
            for (int r = 0; r < 4; ++r)
                lraw[(g * 4 + r) * 28 + oc1] =
                    2.0f / (1.0f + expf(-(v1[r] + bm)));
        }
    }
    __syncthreads();                        // barrier B

    // ---- Phase 2: deform partials over my taps ----
    v4f acc[4];
#pragma unroll
    for (int nt = 0; nt < 4; ++nt) acc[nt] = (v4f){0.f, 0.f, 0.f, 0.f};

    for (int k = t0; k < t1; ++k) {
        int ky = k / 3, kx = k - 3 * ky;
        float dy = lraw[m * 28 + 2 * k];
        float dx = lraw[m * 28 + 2 * k + 1];
        float mm = lraw[m * 28 + 18 + k];

        float py = (float)(y - 1 + ky) + dy;
        float px = (float)(x - 1 + kx) + dx;
        float fy = floorf(py), fx = floorf(px);
        int   y0 = (int)fy,    x0 = (int)fx;
        float wy = py - fy,    wx = px - fx;
        int   y1 = y0 + 1,     x1 = x0 + 1;

        bool y0v = (y0 >= 0) && (y0 < HH);
        bool y1v = (y1 >= 0) && (y1 < HH);
        bool x0v = (x0 >= 0) && (x0 < WW);
        bool x1v = (x1 >= 0) && (x1 < WW);

        float w00 = (1.f - wy) * (1.f - wx) * ((y0v && x0v) ? mm : 0.f);
        float w01 = (1.f - wy) * wx         * ((y0v && x1v) ? mm : 0.f);
        float w10 = wy * (1.f - wx)         * ((y1v && x0v) ? mm : 0.f);
        float w11 = wy * wx                 * ((y1v && x1v) ? mm : 0.f);

        int y0c = min(max(y0, 0), HH - 1), y1c = min(max(y1, 0), HH - 1);
        int x0c = min(max(x0, 0), WW - 1), x1c = min(max(x1, 0), WW - 1);
        int rb = b * HW;
        // fj channels at +64 in the row; lane's A-chunk = ks*32 + g*8
        const unsigned short* r00 = xt + (size_t)(rb + y0c * WW + x0c) * C2B + 64 + g * 8;
        const unsigned short* r01 = xt + (size_t)(rb + y0c * WW + x1c) * C2B + 64 + g * 8;
        const unsigned short* r10 = xt + (size_t)(rb + y1c * WW + x0c) * C2B + 64 + g * 8;
        const unsigned short* r11 = xt + (size_t)(rb + y1c * WW + x1c) * C2B + 64 + g * 8;

        v8s afrag[2];
#pragma unroll
        for (int ks = 0; ks < 2; ++ks) {
            uint4 u00 = *(const uint4*)(r00 + ks * 32);
            uint4 u01 = *(const uint4*)(r01 + ks * 32);
            uint4 u10 = *(const uint4*)(r10 + ks * 32);
            uint4 u11 = *(const uint4*)(r11 + ks * 32);
            uint4 ov;
            ov.x = bil2(u00.x, u01.x, u10.x, u11.x, w00, w01, w10, w11);
            ov.y = bil2(u00.y, u01.y, u10.y, u11.y, w00, w01, w10, w11);
            ov.z = bil2(u00.z, u01.z, u10.z, u11.z, w00, w01, w10, w11);
            ov.w = bil2(u00.w, u01.w, u10.w, u11.w, w00, w01, w10, w11);
            afrag[ks] = __builtin_bit_cast(v8s, ov);
        }

        const unsigned short* wk = wb2 + (size_t)(k * 64 + m) * 64 + g * 8;
#pragma unroll
        for (int nt = 0; nt < 4; ++nt) {
#pragma unroll
            for (int ks = 0; ks < 2; ++ks) {
                v8s bb = *(const v8s*)(wk + nt * 16 * 64 + ks * 32);
                acc[nt] = __builtin_amdgcn_mfma_f32_16x16x32_bf16(
                    afrag[ks], bb, acc[nt], 0, 0, 0);
            }
        }
    }

    {                                       // publish all 16 partials
        float* rb = &red[wid][l * RS];
        *(v4f*)(rb + 0)  = acc[0];
        *(v4f*)(rb + 4)  = acc[1];
        *(v4f*)(rb + 8)  = acc[2];
        *(v4f*)(rb + 12) = acc[3];
    }
    __syncthreads();                        // barrier C
    {                                       // wave w reduces + stores n-tile w
        v4f s = {0.f, 0.f, 0.f, 0.f};
#pragma unroll
        for (int sw = 0; sw < 4; ++sw)
            s += *(const v4f*)(&red[sw][l * RS + wid * 4]);
        // D: row = g*4+reg (position), col = m; o = wid*16 + m
        float* op = out + ((size_t)(b * COUT + wid * 16 + m)) * HW + hw0 + g * 4;
        *(v4f*)op = s;
    }
}

extern "C" void kernel_launch(void* const* d_in, const int* in_sizes, int n_in,
                              void* d_out, int out_size, void* d_ws, size_t ws_size,
                              hipStream_t stream)
{
    const float* frame_i = (const float*)d_in[0];
    const float* frame_j = (const float*)d_in[1];
    const float* flow_ij = (const float*)d_in[2];
    const float* w_off   = (const float*)d_in[3];
    const float* b_off   = (const float*)d_in[4];
    const float* w_mod   = (const float*)d_in[5];
    const float* b_mod   = (const float*)d_in[6];
    const float* w_reg   = (const float*)d_in[7];
    float* out = (float*)d_out;

    // workspace: Xt bf16 [NROW+1][160] | Wa2 | Wb2  (~12 MB)
    unsigned short* xt  = (unsigned short*)d_ws;
    unsigned short* wa2 = xt + (size_t)(NROW + 1) * C2B;
    unsigned short* wb2 = wa2 + NA;

    prep_kernel<<<PXB2 + PWBLK + 1, 256, 0, stream>>>(
        frame_i, frame_j, flow_ij, w_off, w_mod, w_reg, xt, wa2, wb2);

    fused_kernel<<<NSTRIP, 256, 0, stream>>>(
        xt, wa2, wb2, b_off, b_mod, out);
}

// Round 12
// 140.188 us; speedup vs baseline: 1.0176x; 1.0176x over previous
//
#include <hip/hip_runtime.h>
#include <math.h>

#define BB   4
#define HH   96
#define WW   96
#define HW   (HH * WW)          // 9216
#define CIN  64
#define COUT 64
#define C2B  160                // bf16 concat channels padded 130 -> 160
#define NROW (BB * HW)          // 36864
#define ZROW NROW               // all-zero row for invalid conv taps
#define NSTRIP (NROW / 16)      // 2304 strips of 16 positions = fused grid
#define BPX3 (NSTRIP / 8)       // 288 fused blocks per XCD
#define NA   (9 * 32 * C2B)     // wa2 elements (46080)
#define NW   (9 * 64 * 64)      // wb2 elements (36864)
#define PXB2 (NROW / 32)        // 1152 prep X-blocks (64 rows, half channels)
#define PWBLK 324               // weight blocks covering NA+NW elements
#define TS   49                 // prep LDS tile stride (dwords), conflict-free
#define RS   20                 // reduce-buffer stride (floats): 16B aligned

typedef short v8s __attribute__((ext_vector_type(8)));   // 8 bf16 = 4 VGPRs
typedef float v4f __attribute__((ext_vector_type(4)));

__device__ __forceinline__ unsigned short f2bf(float f) {
    unsigned u = __float_as_uint(f);
    return (unsigned short)((u + 0x7FFFu + ((u >> 16) & 1u)) >> 16);  // RTN-even
}
__device__ __forceinline__ unsigned pack2(float a, float b) {
    return (unsigned)f2bf(a) | ((unsigned)f2bf(b) << 16);
}
// bilinear-combine one packed-bf16-pair dword from each of 4 corners
__device__ __forceinline__ unsigned bil2(unsigned a, unsigned b, unsigned c,
                                         unsigned d, float w00, float w01,
                                         float w10, float w11) {
    float lo = w00 * __uint_as_float(a << 16) + w01 * __uint_as_float(b << 16)
             + w10 * __uint_as_float(c << 16) + w11 * __uint_as_float(d << 16);
    float hi = w00 * __uint_as_float(a & 0xffff0000u)
             + w01 * __uint_as_float(b & 0xffff0000u)
             + w10 * __uint_as_float(c & 0xffff0000u)
             + w11 * __uint_as_float(d & 0xffff0000u);
    return pack2(lo, hi);
}

// ---------------------------------------------------------------------------
// Prep (unchanged from R10/R11).
// ---------------------------------------------------------------------------
__global__ __launch_bounds__(256) void prep_kernel(
    const float* __restrict__ fi, const float* __restrict__ fj,
    const float* __restrict__ fl, const float* __restrict__ w_off,
    const float* __restrict__ w_mod, const float* __restrict__ w_reg,
    unsigned short* __restrict__ xt, unsigned short* __restrict__ wa2,
    unsigned short* __restrict__ wb2)
{
    int blk = blockIdx.x;
    if (blk < PXB2) {
        __shared__ __align__(16) unsigned tile[64 * TS];   // 12.5 KB
        int tid = threadIdx.x;
        int p = tid & 63, cg = tid >> 6;    // position, channel-group 0..3
        int u = blk >> 1, half = blk & 1;
        int r0 = u * 64;
        int b = r0 / HW;                    // 64-row strip never straddles b
        int hw = r0 - b * HW + p;
        uint4* dst = (uint4*)(xt + (size_t)r0 * C2B);      // 20 quads per row
        if (half == 0) {                    // fi -> dwords 0..31
            const float* pi = fi + (size_t)b * CIN * HW + hw;
#pragma unroll
            for (int d = 0; d < 8; ++d) {
                int c = cg * 16 + 2 * d;
                tile[p * TS + cg * 8 + d] =
                    pack2(pi[(size_t)c * HW], pi[(size_t)(c + 1) * HW]);
            }
            __syncthreads();
#pragma unroll
            for (int i = 0; i < 2; ++i) {   // 512 quads: 8 per row
                int gq = i * 256 + tid;
                int rl = gq >> 3, c4 = gq & 7;
                const unsigned* s = &tile[rl * TS + c4 * 4];
                uint4 v = {s[0], s[1], s[2], s[3]};
                dst[rl * 20 + c4] = v;
            }
        } else {                            // fj+flow+pad -> dwords 32..79
            const float* pj = fj + (size_t)b * CIN * HW + hw;
#pragma unroll
            for (int d = 0; d < 8; ++d) {
                int c = cg * 16 + 2 * d;
                tile[p * TS + cg * 8 + d] =
                    pack2(pj[(size_t)c * HW], pj[(size_t)(c + 1) * HW]);
            }
            if (cg == 0) {
                const float* pf = fl + (size_t)b * 2 * HW + hw;
                tile[p * TS + 32] = pack2(pf[0], pf[HW]);
#pragma unroll
                for (int i = 33; i < 48; ++i) tile[p * TS + i] = 0u;
            }
            __syncthreads();
#pragma unroll
            for (int i = 0; i < 3; ++i) {   // 768 quads: 12 per row
                int gq = i * 256 + tid;
                int rl = gq / 12, c4 = gq - rl * 12;
                const unsigned* s = &tile[rl * TS + c4 * 4];
                uint4 v = {s[0], s[1], s[2], s[3]};
                dst[rl * 20 + 8 + c4] = v;
            }
        }
    } else if (blk < PXB2 + PWBLK) {
        int e = (blk - PXB2) * 256 + threadIdx.x;
        if (e < NA) {
            int c  = e % C2B;
            int oc = (e / C2B) % 32;
            int t  = e / (C2B * 32);
            float v = 0.0f;
            if (oc < 27 && c < 130) {
                if (oc < 18) v = w_off[((size_t)oc * 130 + c) * 9 + t];
                else         v = w_mod[((size_t)(oc - 18) * 130 + c) * 9 + t];
            }
            wa2[e] = f2bf(v);
        } else {
            int e2 = e - NA;
            if (e2 < NW) {
                int c = e2 % 64;
                int o = (e2 / 64) % 64;
                int k = e2 / 4096;
                wb2[e2] = f2bf(w_reg[((size_t)o * 64 + c) * 9 + k]);
            }
        }
    } else {
        if (threadIdx.x < 20) {             // zero row, 20 dwordx4
            uint4 z = {0u, 0u, 0u, 0u};
            ((uint4*)(xt + (size_t)ZROW * C2B))[threadIdx.x] = z;
        }
    }
}

// ---------------------------------------------------------------------------
// Fused conv + deform, 4-way K-split, 1 strip/block (R11 layout) with
// ILP-first restructure: __launch_bounds__(256,2) lifts the VGPR cap 60->256
// so BOTH phases can batch-issue their entire load stream before consuming:
//  Phase 1: preload ALL my taps' A-fragments (<=15 dwordx4) -> then the
//    weight-load + MFMA loop (weights are L1-hot across blocks).
//  Phase 2: read lraw + compute corner addrs/weights for ALL my taps, issue
//    ALL gathers (<=24 dwordx4) -> then bil2 + MFMA per tap.
// This collapses ~9 serial L2 round-trips per wave into ~2.
// ---------------------------------------------------------------------------
__global__ __launch_bounds__(256, 2) void fused_kernel(
    const unsigned short* __restrict__ xt,
    const unsigned short* __restrict__ wa2,
    const unsigned short* __restrict__ wb2,
    const float* __restrict__ b_off, const float* __restrict__ b_mod,
    float* __restrict__ out)
{
    __shared__ float lraw[16 * 28];                   // 1.8 KB offsets/mods
    __shared__ __align__(16) float red[4][64 * RS];   // 20.5 KB partials

    int l = threadIdx.x & 63;
    int wid = __builtin_amdgcn_readfirstlane(threadIdx.x >> 6);
    int m = l & 15, g = l >> 4;
    int strip = (blockIdx.x & 7) * BPX3 + (blockIdx.x >> 3);  // XCD-contiguous
    int b = strip / (HW / 16);              // wave-uniform
    int hw0 = (strip - b * (HW / 16)) * 16;
    int hw = hw0 + m;
    int x = hw % WW, y = hw / WW;
    int t0 = wid * 2;
    int ntap = (wid == 3) ? 3 : 2;          // wave-uniform tap count

    // ---- Phase 1: conv partials. Preload ALL A-fragments first. ----
    v8s afr[3][5];
#pragma unroll
    for (int ti = 0; ti < 3; ++ti) {
        if (ti < ntap) {
            int t = t0 + ti;
            int ty = t / 3, tx = t - 3 * ty;
            int yy = y + ty - 1, xx = x + tx - 1;
            bool ok = ((unsigned)yy < HH) && ((unsigned)xx < WW);
            int row = ok ? (b * HW + yy * WW + xx) : ZROW;
            const unsigned short* ar = xt + (size_t)row * C2B + g * 8;
#pragma unroll
            for (int ks = 0; ks < 5; ++ks)
                afr[ti][ks] = *(const v8s*)(ar + ks * 32);
        }
    }

    v4f acc0 = {0.f, 0.f, 0.f, 0.f};
    v4f acc1 = {0.f, 0.f, 0.f, 0.f};
#pragma unroll
    for (int ti = 0; ti < 3; ++ti) {
        if (ti < ntap) {
            int t = t0 + ti;
            const unsigned short* w0 = wa2 + ((size_t)(t * 32 + m)) * C2B + g * 8;
            const unsigned short* w1 = w0 + 16 * C2B;
#pragma unroll
            for (int ks = 0; ks < 5; ++ks) {
                v8s b0 = *(const v8s*)(w0 + ks * 32);
                v8s b1 = *(const v8s*)(w1 + ks * 32);
                acc0 = __builtin_amdgcn_mfma_f32_16x16x32_bf16(afr[ti][ks], b0, acc0, 0, 0, 0);
                acc1 = __builtin_amdgcn_mfma_f32_16x16x32_bf16(afr[ti][ks], b1, acc1, 0, 0, 0);
            }
        }
    }

    if (wid != 0) {                         // publish partials
        float* rb = &red[wid][l * RS];
        *(v4f*)(rb + 0) = acc0;
        *(v4f*)(rb + 4) = acc1;
    }
    __syncthreads();                        // barrier A
    if (wid == 0) {                         // reduce + epilogue -> lraw
#pragma unroll
        for (int sw = 1; sw < 4; ++sw) {
            const float* rb = &red[sw][l * RS];
            acc0 += *(const v4f*)(rb + 0);
            acc1 += *(const v4f*)(rb + 4);
        }
        float v0[4] = {acc0.x, acc0.y, acc0.z, acc0.w};
        float v1[4] = {acc1.x, acc1.y, acc1.z, acc1.w};
        float bo0 = b_off[m];
        int oc1 = 16 + m;
#pragma unroll
        for (int r = 0; r < 4; ++r)
            lraw[(g * 4 + r) * 28 + m] = v0[r] + bo0;
        if (oc1 < 18) {
            float bo1 = b_off[oc1];
#pragma unroll
            for (int r = 0; r < 4; ++r)
                lraw[(g * 4 + r) * 28 + oc1] = v1[r] + bo1;
        } else if (oc1 < 27) {
            float bm = b_mod[oc1 - 18];
#pragma unroll
            for (int r = 0; r < 4; ++r)
                lraw[(g * 4 + r) * 28 + oc1] =
                    2.0f / (1.0f + expf(-(v1[r] + bm)));
        }
    }
    __syncthreads();                        // barrier B

    // ---- Phase 2: deform. Compute all tap weights/addrs, issue all gathers.
    float cw[3][4];                         // bilinear*mod weights per tap
    uint4 gbuf[3][8];                       // gathered corners [tap][ks*4+corner]
#pragma unroll
    for (int ti = 0; ti < 3; ++ti) {
        if (ti < ntap) {
            int k = t0 + ti;
            int ky = k / 3, kx = k - 3 * ky;
            float dy = lraw[m * 28 + 2 * k];
            float dx = lraw[m * 28 + 2 * k + 1];
            float mm = lraw[m * 28 + 18 + k];

            float py = (float)(y - 1 + ky) + dy;
            float px = (float)(x - 1 + kx) + dx;
            float fy = floorf(py), fx = floorf(px);
            int   y0 = (int)fy,    x0 = (int)fx;
            float wy = py - fy,    wx = px - fx;
            int   y1 = y0 + 1,     x1 = x0 + 1;

            bool y0v = (y0 >= 0) && (y0 < HH);
            bool y1v = (y1 >= 0) && (y1 < HH);
            bool x0v = (x0 >= 0) && (x0 < WW);
            bool x1v = (x1 >= 0) && (x1 < WW);

            cw[ti][0] = (1.f - wy) * (1.f - wx) * ((y0v && x0v) ? mm : 0.f);
            cw[ti][1] = (1.f - wy) * wx         * ((y0v && x1v) ? mm : 0.f);
            cw[ti][2] = wy * (1.f - wx)         * ((y1v && x0v) ? mm : 0.f);
            cw[ti][3] = wy * wx                 * ((y1v && x1v) ? mm : 0.f);

            int y0c = min(max(y0, 0), HH - 1), y1c = min(max(y1, 0), HH - 1);
            int x0c = min(max(x0, 0), WW - 1), x1c = min(max(x1, 0), WW - 1);
            int rb = b * HW;
            const unsigned short* r00 = xt + (size_t)(rb + y0c * WW + x0c) * C2B + 64 + g * 8;
            const unsigned short* r01 = xt + (size_t)(rb + y0c * WW + x1c) * C2B + 64 + g * 8;
            const unsigned short* r10 = xt + (size_t)(rb + y1c * WW + x0c) * C2B + 64 + g * 8;
            const unsigned short* r11 = xt + (size_t)(rb + y1c * WW + x1c) * C2B + 64 + g * 8;
#pragma unroll
            for (int ks = 0; ks < 2; ++ks) {
                gbuf[ti][ks * 4 + 0] = *(const uint4*)(r00 + ks * 32);
                gbuf[ti][ks * 4 + 1] = *(const uint4*)(r01 + ks * 32);
                gbuf[ti][ks * 4 + 2] = *(const uint4*)(r10 + ks * 32);
                gbuf[ti][ks * 4 + 3] = *(const uint4*)(r11 + ks * 32);
            }
        }
    }

    v4f acc[4];
#pragma unroll
    for (int nt = 0; nt < 4; ++nt) acc[nt] = (v4f){0.f, 0.f, 0.f, 0.f};

#pragma unroll
    for (int ti = 0; ti < 3; ++ti) {
        if (ti < ntap) {
            int k = t0 + ti;
            float w00 = cw[ti][0], w01 = cw[ti][1];
            float w10 = cw[ti][2], w11 = cw[ti][3];
            v8s afrag[2];
#pragma unroll
            for (int ks = 0; ks < 2; ++ks) {
                uint4 u00 = gbuf[ti][ks * 4 + 0];
                uint4 u01 = gbuf[ti][ks * 4 + 1];
                uint4 u10 = gbuf[ti][ks * 4 + 2];
                uint4 u11 = gbuf[ti][ks * 4 + 3];
                uint4 ov;
                ov.x = bil2(u00.x, u01.x, u10.x, u11.x, w00, w01, w10, w11);
                ov.y = bil2(u00.y, u01.y, u10.y, u11.y, w00, w01, w10, w11);
                ov.z = bil2(u00.z, u01.z, u10.z, u11.z, w00, w01, w10, w11);
                ov.w = bil2(u00.w, u01.w, u10.w, u11.w, w00, w01, w10, w11);
                afrag[ks] = __builtin_bit_cast(v8s, ov);
            }
            const unsigned short* wk = wb2 + (size_t)(k * 64 + m) * 64 + g * 8;
#pragma unroll
            for (int nt = 0; nt < 4; ++nt) {
#pragma unroll
                for (int ks = 0; ks < 2; ++ks) {
                    v8s bb = *(const v8s*)(wk + nt * 16 * 64 + ks * 32);
                    acc[nt] = __builtin_amdgcn_mfma_f32_16x16x32_bf16(
                        afrag[ks], bb, acc[nt], 0, 0, 0);
                }
            }
        }
    }

    {                                       // publish all 16 partials
        float* rb = &red[wid][l * RS];
        *(v4f*)(rb + 0)  = acc[0];
        *(v4f*)(rb + 4)  = acc[1];
        *(v4f*)(rb + 8)  = acc[2];
        *(v4f*)(rb + 12) = acc[3];
    }
    __syncthreads();                        // barrier C
    {                                       // wave w reduces + stores n-tile w
        v4f s = {0.f, 0.f, 0.f, 0.f};
#pragma unroll
        for (int sw = 0; sw < 4; ++sw)
            s += *(const v4f*)(&red[sw][l * RS + wid * 4]);
        // D: row = g*4+reg (position), col = m; o = wid*16 + m
        float* op = out + ((size_t)(b * COUT + wid * 16 + m)) * HW + hw0 + g * 4;
        *(v4f*)op = s;
    }
}

extern "C" void kernel_launch(void* const* d_in, const int* in_sizes, int n_in,
                              void* d_out, int out_size, void* d_ws, size_t ws_size,
                              hipStream_t stream)
{
    const float* frame_i = (const float*)d_in[0];
    const float* frame_j = (const float*)d_in[1];
    const float* flow_ij = (const float*)d_in[2];
    const float* w_off   = (const float*)d_in[3];
    const float* b_off   = (const float*)d_in[4];
    const float* w_mod   = (const float*)d_in[5];
    const float* b_mod   = (const float*)d_in[6];
    const float* w_reg   = (const float*)d_in[7];
    float* out = (float*)d_out;

    // workspace: Xt bf16 [NROW+1][160] | Wa2 | Wb2  (~12 MB)
    unsigned short* xt  = (unsigned short*)d_ws;
    unsigned short* wa2 = xt + (size_t)(NROW + 1) * C2B;
    unsigned short* wb2 = wa2 + NA;

    prep_kernel<<<PXB2 + PWBLK + 1, 256, 0, stream>>>(
        frame_i, frame_j, flow_ij, w_off, w_mod, w_reg, xt, wa2, wb2);

    fused_kernel<<<NSTRIP, 256, 0, stream>>>(
        xt, wa2, wb2, b_off, b_mod, out);
}

// Round 13
// 134.788 us; speedup vs baseline: 1.0584x; 1.0401x over previous
//
#include <hip/hip_runtime.h>
#include <math.h>

#define BB   4
#define HH   96
#define WW   96
#define HW   (HH * WW)          // 9216
#define CIN  64
#define COUT 64
#define C2B  192                // bf16 row: fi[64] fj[64] flow[2] pad[62]
                                // 384 B = 3 x 128-B cache lines; fj at +128 B (aligned)
#define NROW (BB * HW)          // 36864
#define ZROW NROW               // all-zero row for invalid conv taps
#define NSTRIP (NROW / 16)      // 2304 strips of 16 positions = fused grid
#define BPX3 (NSTRIP / 8)       // 288 fused blocks per XCD
#define NA   (9 * 5 * 2 * 512)  // wa2f elements (46080), fragment-dense
#define NW   (9 * 2 * 4 * 512)  // wb2f elements (36864), fragment-dense
#define PXB2 (NROW / 32)        // 1152 prep X-blocks (64 rows, half channels)
#define PWBLK 324               // weight blocks covering NA+NW elements
#define TSX  35                 // prep LDS tile stride (dwords): 35%32=3,
                                // gcd(3,32)=1 -> conflict-free
#define RS   20                 // reduce-buffer stride (floats)

typedef short v8s __attribute__((ext_vector_type(8)));   // 8 bf16 = 4 VGPRs
typedef float v4f __attribute__((ext_vector_type(4)));

__device__ __forceinline__ unsigned short f2bf(float f) {
    unsigned u = __float_as_uint(f);
    return (unsigned short)((u + 0x7FFFu + ((u >> 16) & 1u)) >> 16);  // RTN-even
}
__device__ __forceinline__ unsigned pack2(float a, float b) {
    return (unsigned)f2bf(a) | ((unsigned)f2bf(b) << 16);
}
__device__ __forceinline__ unsigned bil2(unsigned a, unsigned b, unsigned c,
                                         unsigned d, float w00, float w01,
                                         float w10, float w11) {
    float lo = w00 * __uint_as_float(a << 16) + w01 * __uint_as_float(b << 16)
             + w10 * __uint_as_float(c << 16) + w11 * __uint_as_float(d << 16);
    float hi = w00 * __uint_as_float(a & 0xffff0000u)
             + w01 * __uint_as_float(b & 0xffff0000u)
             + w10 * __uint_as_float(c & 0xffff0000u)
             + w11 * __uint_as_float(d & 0xffff0000u);
    return pack2(lo, hi);
}

// ---------------------------------------------------------------------------
// Prep. X-blocks: 64 rows x half the row each (even blk: fi -> dwords 0..31;
// odd blk: fj+flow+zero-pad -> dwords 32..95). Weight blocks fill wa2f/wb2f
// in MFMA-FRAGMENT-DENSE order so the fused kernel's weight loads are fully
// contiguous 1KB wave-loads:
//   wa2f[((t*5+ks)*2+nt)*512 + l*8 + e] = Wconv[oc=nt*16+(l&15)][ch=ks*32+(l>>4)*8+e]
//   wb2f[((k*2+ks)*4+nt)*512 + l*8 + e] = w_reg[o=nt*16+(l&15)][c=ks*32+(l>>4)*8+e][k]
// ---------------------------------------------------------------------------
__global__ __launch_bounds__(256) void prep_kernel(
    const float* __restrict__ fi, const float* __restrict__ fj,
    const float* __restrict__ fl, const float* __restrict__ w_off,
    const float* __restrict__ w_mod, const float* __restrict__ w_reg,
    unsigned short* __restrict__ xt, unsigned short* __restrict__ wa2f,
    unsigned short* __restrict__ wb2f)
{
    int blk = blockIdx.x;
    if (blk < PXB2) {
        __shared__ __align__(16) unsigned tile[64 * TSX];  // 9 KB
        int tid = threadIdx.x;
        int p = tid & 63, cg = tid >> 6;    // position, channel-group 0..3
        int u = blk >> 1, half = blk & 1;
        int r0 = u * 64;
        int b = r0 / HW;                    // 64-row strip never straddles b
        int hw = r0 - b * HW + p;
        uint4* dst = (uint4*)(xt + (size_t)r0 * C2B);      // 24 quads per row
        if (half == 0) {                    // fi -> dwords 0..31
            const float* pi = fi + (size_t)b * CIN * HW + hw;
#pragma unroll
            for (int d = 0; d < 8; ++d) {
                int c = cg * 16 + 2 * d;
                tile[p * TSX + cg * 8 + d] =
                    pack2(pi[(size_t)c * HW], pi[(size_t)(c + 1) * HW]);
            }
            __syncthreads();
#pragma unroll
            for (int i = 0; i < 2; ++i) {   // 512 quads: 8 per row
                int gq = i * 256 + tid;
                int rl = gq >> 3, c4 = gq & 7;
                const unsigned* s = &tile[rl * TSX + c4 * 4];
                uint4 v = {s[0], s[1], s[2], s[3]};
                dst[rl * 24 + c4] = v;
            }
        } else {                            // fj+flow+pad -> dwords 32..95
            const float* pj = fj + (size_t)b * CIN * HW + hw;
#pragma unroll
            for (int d = 0; d < 8; ++d) {
                int c = cg * 16 + 2 * d;
                tile[p * TSX + cg * 8 + d] =
                    pack2(pj[(size_t)c * HW], pj[(size_t)(c + 1) * HW]);
            }
            if (cg == 0) {
                const float* pf = fl + (size_t)b * 2 * HW + hw;
                tile[p * TSX + 32] = pack2(pf[0], pf[HW]);
            }
            __syncthreads();
#pragma unroll
            for (int i = 0; i < 4; ++i) {   // 1024 quads: 16 per row (8..23)
                int gq = i * 256 + tid;
                int rl = gq >> 4, c4 = gq & 15;
                uint4 v = {0u, 0u, 0u, 0u};
                if (c4 < 8) {
                    const unsigned* s = &tile[rl * TSX + c4 * 4];
                    v.x = s[0]; v.y = s[1]; v.z = s[2]; v.w = s[3];
                } else if (c4 == 8) {
                    v.x = tile[rl * TSX + 32];
                }
                dst[rl * 24 + 8 + c4] = v;
            }
        }
    } else if (blk < PXB2 + PWBLK) {
        int e = (blk - PXB2) * 256 + threadIdx.x;
        if (e < NA) {                       // wa2f, fragment-dense
            int t  = e / 5120;
            int r1 = e - t * 5120;
            int ks = r1 >> 10;
            int r2 = r1 & 1023;
            int nt = r2 >> 9;
            int l9 = r2 & 511;
            int l  = l9 >> 3, ee = l9 & 7;
            int m  = l & 15, g = l >> 4;
            int oc = nt * 16 + m;
            int ch = ks * 32 + g * 8 + ee;
            float v = 0.0f;
            if (oc < 27 && ch < 130) {
                if (oc < 18) v = w_off[((size_t)oc * 130 + ch) * 9 + t];
                else         v = w_mod[((size_t)(oc - 18) * 130 + ch) * 9 + t];
            }
            wa2f[e] = f2bf(v);
        } else {
            int e2 = e - NA;
            if (e2 < NW) {                  // wb2f, fragment-dense
                int k  = e2 >> 12;
                int r1 = e2 & 4095;
                int ks = r1 >> 11;
                int r2 = r1 & 2047;
                int nt = r2 >> 9;
                int l9 = r2 & 511;
                int l  = l9 >> 3, ee = l9 & 7;
                int m  = l & 15, g = l >> 4;
                int o  = nt * 16 + m;
                int c  = ks * 32 + g * 8 + ee;
                wb2f[e2] = f2bf(w_reg[((size_t)o * 64 + c) * 9 + k]);
            }
        }
    } else {
        if (threadIdx.x < 24) {             // zero row, 24 dwordx4
            uint4 z = {0u, 0u, 0u, 0u};
            ((uint4*)(xt + (size_t)ZROW * C2B))[threadIdx.x] = z;
        }
    }
}

// ---------------------------------------------------------------------------
// Fused conv + deform, 4-way K-split, 1 strip/block. R13 changes:
//  - weight loads are fragment-dense contiguous 1KB wave-loads (wa2f/wb2f)
//  - sched_barrier(0) after phase-1 preload and phase-2 gather-issue forces
//    the loads to stay batched (in-flight) instead of being sunk to uses
//  - Xt rows are 384 B (3 cache lines), fj region 128-B aligned
// ---------------------------------------------------------------------------
__global__ __launch_bounds__(256, 2) void fused_kernel(
    const unsigned short* __restrict__ xt,
    const unsigned short* __restrict__ wa2f,
    const unsigned short* __restrict__ wb2f,
    const float* __restrict__ b_off, const float* __restrict__ b_mod,
    float* __restrict__ out)
{
    __shared__ float lraw[16 * 28];                   // 1.8 KB offsets/mods
    __shared__ __align__(16) float red[4][64 * RS];   // 20.5 KB partials

    int l = threadIdx.x & 63;
    int wid = __builtin_amdgcn_readfirstlane(threadIdx.x >> 6);
    int m = l & 15, g = l >> 4;
    int strip = (blockIdx.x & 7) * BPX3 + (blockIdx.x >> 3);  // XCD-contiguous
    int b = strip / (HW / 16);              // wave-uniform
    int hw0 = (strip - b * (HW / 16)) * 16;
    int hw = hw0 + m;
    int x = hw % WW, y = hw / WW;
    int t0 = wid * 2;
    int ntap = (wid == 3) ? 3 : 2;          // wave-uniform tap count

    // ---- Phase 1: preload ALL my taps' A-fragments, then MFMA loop ----
    v8s afr[3][5];
#pragma unroll
    for (int ti = 0; ti < 3; ++ti) {
        if (ti < ntap) {
            int t = t0 + ti;
            int ty = t / 3, tx = t - 3 * ty;
            int yy = y + ty - 1, xx = x + tx - 1;
            bool ok = ((unsigned)yy < HH) && ((unsigned)xx < WW);
            int row = ok ? (b * HW + yy * WW + xx) : ZROW;
            const unsigned short* ar = xt + (size_t)row * C2B + g * 8;
#pragma unroll
            for (int ks = 0; ks < 5; ++ks)
                afr[ti][ks] = *(const v8s*)(ar + ks * 32);
        }
    }
    __builtin_amdgcn_sched_barrier(0);      // keep preloads batched in flight

    v4f acc0 = {0.f, 0.f, 0.f, 0.f};
    v4f acc1 = {0.f, 0.f, 0.f, 0.f};
#pragma unroll
    for (int ti = 0; ti < 3; ++ti) {
        if (ti < ntap) {
            int t = t0 + ti;
#pragma unroll
            for (int ks = 0; ks < 5; ++ks) {
                const unsigned short* wp =
                    wa2f + ((size_t)((t * 5 + ks) * 2)) * 512 + l * 8;
                v8s b0 = *(const v8s*)(wp);
                v8s b1 = *(const v8s*)(wp + 512);
                acc0 = __builtin_amdgcn_mfma_f32_16x16x32_bf16(afr[ti][ks], b0, acc0, 0, 0, 0);
                acc1 = __builtin_amdgcn_mfma_f32_16x16x32_bf16(afr[ti][ks], b1, acc1, 0, 0, 0);
            }
        }
    }

    if (wid != 0) {                         // publish partials
        float* rb = &red[wid][l * RS];
        *(v4f*)(rb + 0) = acc0;
        *(v4f*)(rb + 4) = acc1;
    }
    __syncthreads();                        // barrier A
    if (wid == 0) {                         // reduce + epilogue -> lraw
#pragma unroll
        for (int sw = 1; sw < 4; ++sw) {
            const float* rb = &red[sw][l * RS];
            acc0 += *(const v4f*)(rb + 0);
            acc1 += *(const v4f*)(rb + 4);
        }
        float v0[4] = {acc0.x, acc0.y, acc0.z, acc0.w};
        float v1[4] = {acc1.x, acc1.y, acc1.z, acc1.w};
        float bo0 = b_off[m];
        int oc1 = 16 + m;
#pragma unroll
        for (int r = 0; r < 4; ++r)
            lraw[(g * 4 + r) * 28 + m] = v0[r] + bo0;
        if (oc1 < 18) {
            float bo1 = b_off[oc1];
#pragma unroll
            for (int r = 0; r < 4; ++r)
                lraw[(g * 4 + r) * 28 + oc1] = v1[r] + bo1;
        } else if (oc1 < 27) {
            float bm = b_mod[oc1 - 18];
#pragma unroll
            for (int r = 0; r < 4; ++r)
                lraw[(g * 4 + r) * 28 + oc1] =
                    2.0f / (1.0f + expf(-(v1[r] + bm)));
        }
    }
    __syncthreads();                        // barrier B

    // ---- Phase 2: compute all tap weights/addrs, issue ALL gathers ----
    float cw[3][4];
    uint4 gbuf[3][8];                       // [tap][ks*4+corner]
#pragma unroll
    for (int ti = 0; ti < 3; ++ti) {
        if (ti < ntap) {
            int k = t0 + ti;
            int ky = k / 3, kx = k - 3 * ky;
            float dy = lraw[m * 28 + 2 * k];
            float dx = lraw[m * 28 + 2 * k + 1];
            float mm = lraw[m * 28 + 18 + k];

            float py = (float)(y - 1 + ky) + dy;
            float px = (float)(x - 1 + kx) + dx;
            float fy = floorf(py), fx = floorf(px);
            int   y0 = (int)fy,    x0 = (int)fx;
            float wy = py - fy,    wx = px - fx;
            int   y1 = y0 + 1,     x1 = x0 + 1;

            bool y0v = (y0 >= 0) && (y0 < HH);
            bool y1v = (y1 >= 0) && (y1 < HH);
            bool x0v = (x0 >= 0) && (x0 < WW);
            bool x1v = (x1 >= 0) && (x1 < WW);

            cw[ti][0] = (1.f - wy) * (1.f - wx) * ((y0v && x0v) ? mm : 0.f);
            cw[ti][1] = (1.f - wy) * wx         * ((y0v && x1v) ? mm : 0.f);
            cw[ti][2] = wy * (1.f - wx)         * ((y1v && x0v) ? mm : 0.f);
            cw[ti][3] = wy * wx                 * ((y1v && x1v) ? mm : 0.f);

            int y0c = min(max(y0, 0), HH - 1), y1c = min(max(y1, 0), HH - 1);
            int x0c = min(max(x0, 0), WW - 1), x1c = min(max(x1, 0), WW - 1);
            int rb = b * HW;
            const unsigned short* r00 = xt + (size_t)(rb + y0c * WW + x0c) * C2B + 64 + g * 8;
            const unsigned short* r01 = xt + (size_t)(rb + y0c * WW + x1c) * C2B + 64 + g * 8;
            const unsigned short* r10 = xt + (size_t)(rb + y1c * WW + x0c) * C2B + 64 + g * 8;
            const unsigned short* r11 = xt + (size_t)(rb + y1c * WW + x1c) * C2B + 64 + g * 8;
#pragma unroll
            for (int ks = 0; ks < 2; ++ks) {
                gbuf[ti][ks * 4 + 0] = *(const uint4*)(r00 + ks * 32);
                gbuf[ti][ks * 4 + 1] = *(const uint4*)(r01 + ks * 32);
                gbuf[ti][ks * 4 + 2] = *(const uint4*)(r10 + ks * 32);
                gbuf[ti][ks * 4 + 3] = *(const uint4*)(r11 + ks * 32);
            }
        }
    }
    __builtin_amdgcn_sched_barrier(0);      // keep gathers batched in flight

    v4f acc[4];
#pragma unroll
    for (int nt = 0; nt < 4; ++nt) acc[nt] = (v4f){0.f, 0.f, 0.f, 0.f};

#pragma unroll
    for (int ti = 0; ti < 3; ++ti) {
        if (ti < ntap) {
            int k = t0 + ti;
            float w00 = cw[ti][0], w01 = cw[ti][1];
            float w10 = cw[ti][2], w11 = cw[ti][3];
            v8s afrag[2];
#pragma unroll
            for (int ks = 0; ks < 2; ++ks) {
                uint4 u00 = gbuf[ti][ks * 4 + 0];
                uint4 u01 = gbuf[ti][ks * 4 + 1];
                uint4 u10 = gbuf[ti][ks * 4 + 2];
                uint4 u11 = gbuf[ti][ks * 4 + 3];
                uint4 ov;
                ov.x = bil2(u00.x, u01.x, u10.x, u11.x, w00, w01, w10, w11);
                ov.y = bil2(u00.y, u01.y, u10.y, u11.y, w00, w01, w10, w11);
                ov.z = bil2(u00.z, u01.z, u10.z, u11.z, w00, w01, w10, w11);
                ov.w = bil2(u00.w, u01.w, u10.w, u11.w, w00, w01, w10, w11);
                afrag[ks] = __builtin_bit_cast(v8s, ov);
            }
#pragma unroll
            for (int nt = 0; nt < 4; ++nt) {
#pragma unroll
                for (int ks = 0; ks < 2; ++ks) {
                    const unsigned short* wp =
                        wb2f + ((size_t)((k * 2 + ks) * 4 + nt)) * 512 + l * 8;
                    v8s bb = *(const v8s*)wp;
                    acc[nt] = __builtin_amdgcn_mfma_f32_16x16x32_bf16(
                        afrag[ks], bb, acc[nt], 0, 0, 0);
                }
            }
        }
    }

    {                                       // publish all 16 partials
        float* rb = &red[wid][l * RS];
        *(v4f*)(rb + 0)  = acc[0];
        *(v4f*)(rb + 4)  = acc[1];
        *(v4f*)(rb + 8)  = acc[2];
        *(v4f*)(rb + 12) = acc[3];
    }
    __syncthreads();                        // barrier C
    {                                       // wave w reduces + stores n-tile w
        v4f s = {0.f, 0.f, 0.f, 0.f};
#pragma unroll
        for (int sw = 0; sw < 4; ++sw)
            s += *(const v4f*)(&red[sw][l * RS + wid * 4]);
        float* op = out + ((size_t)(b * COUT + wid * 16 + m)) * HW + hw0 + g * 4;
        *(v4f*)op = s;
    }
}

extern "C" void kernel_launch(void* const* d_in, const int* in_sizes, int n_in,
                              void* d_out, int out_size, void* d_ws, size_t ws_size,
                              hipStream_t stream)
{
    const float* frame_i = (const float*)d_in[0];
    const float* frame_j = (const float*)d_in[1];
    const float* flow_ij = (const float*)d_in[2];
    const float* w_off   = (const float*)d_in[3];
    const float* b_off   = (const float*)d_in[4];
    const float* w_mod   = (const float*)d_in[5];
    const float* b_mod   = (const float*)d_in[6];
    const float* w_reg   = (const float*)d_in[7];
    float* out = (float*)d_out;

    // workspace: Xt bf16 [NROW+1][192] | Wa2f | Wb2f  (~14.3 MB)
    unsigned short* xt   = (unsigned short*)d_ws;
    unsigned short* wa2f = xt + (size_t)(NROW + 1) * C2B;
    unsigned short* wb2f = wa2f + NA;

    prep_kernel<<<PXB2 + PWBLK + 1, 256, 0, stream>>>(
        frame_i, frame_j, flow_ij, w_off, w_mod, w_reg, xt, wa2f, wb2f);

    fused_kernel<<<NSTRIP, 256, 0, stream>>>(
        xt, wa2f, wb2f, b_off, b_mod, out);
}

// Round 14
// 128.534 us; speedup vs baseline: 1.1099x; 1.0487x over previous
//
#include <hip/hip_runtime.h>
#include <math.h>

#define BB   4
#define HH   96
#define WW   96
#define HW   (HH * WW)          // 9216
#define CIN  64
#define COUT 64
#define C2B  192                // bf16 row: fi[64] fj[64](permuted) flow[2] pad
                                // 384 B = 3 x 128-B lines; fj region 128-B aligned
#define NROW (BB * HW)          // 36864
#define ZROW NROW               // all-zero row (kept for safety)
#define NSTRIP (NROW / 16)      // 2304 strips of 16 positions = fused grid
#define BPX3 (NSTRIP / 8)       // 288 fused blocks per XCD
#define NA   (9 * 5 * 2 * 512)  // wa2f elements (46080), fragment-dense
#define NW   (9 * 2 * 4 * 512)  // wb2f elements (36864), fragment-dense
#define PXB2 (NROW / 32)        // 1152 prep X-blocks (64 rows, half channels)
#define PWBLK 324               // weight blocks covering NA+NW elements
#define TSX  35                 // prep LDS tile stride (dwords), conflict-free
#define RS   20                 // reduce-buffer stride (floats)
#define PR   55                 // patch row-dim (54 rows + 1 pad -> 2-way banks)

typedef short v8s __attribute__((ext_vector_type(8)));   // 8 bf16 = 4 VGPRs
typedef float v4f __attribute__((ext_vector_type(4)));

__device__ __forceinline__ unsigned short f2bf(float f) {
    unsigned u = __float_as_uint(f);
    return (unsigned short)((u + 0x7FFFu + ((u >> 16) & 1u)) >> 16);  // RTN-even
}
__device__ __forceinline__ unsigned pack2(float a, float b) {
    return (unsigned)f2bf(a) | ((unsigned)f2bf(b) << 16);
}
__device__ __forceinline__ unsigned bil2(unsigned a, unsigned b, unsigned c,
                                         unsigned d, float w00, float w01,
                                         float w10, float w11) {
    float lo = w00 * __uint_as_float(a << 16) + w01 * __uint_as_float(b << 16)
             + w10 * __uint_as_float(c << 16) + w11 * __uint_as_float(d << 16);
    float hi = w00 * __uint_as_float(a & 0xffff0000u)
             + w01 * __uint_as_float(b & 0xffff0000u)
             + w10 * __uint_as_float(c & 0xffff0000u)
             + w11 * __uint_as_float(d & 0xffff0000u);
    return pack2(lo, hi);
}

// ---------------------------------------------------------------------------
// Prep (R13 structure). ONE change: fj chunks stored PERMUTED within the row
// (orig chunk o -> physical (o&3)*2+(o>>2)) so a deform lane's two K-chunks
// are address-adjacent (+0/+16B). Conv reads remap at compile time.
// ---------------------------------------------------------------------------
__global__ __launch_bounds__(256) void prep_kernel(
    const float* __restrict__ fi, const float* __restrict__ fj,
    const float* __restrict__ fl, const float* __restrict__ w_off,
    const float* __restrict__ w_mod, const float* __restrict__ w_reg,
    unsigned short* __restrict__ xt, unsigned short* __restrict__ wa2f,
    unsigned short* __restrict__ wb2f)
{
    int blk = blockIdx.x;
    if (blk < PXB2) {
        __shared__ __align__(16) unsigned tile[64 * TSX];  // 9 KB
        int tid = threadIdx.x;
        int p = tid & 63, cg = tid >> 6;    // position, channel-group 0..3
        int u = blk >> 1, half = blk & 1;
        int r0 = u * 64;
        int b = r0 / HW;                    // 64-row strip never straddles b
        int hw = r0 - b * HW + p;
        uint4* dst = (uint4*)(xt + (size_t)r0 * C2B);      // 24 quads per row
        if (half == 0) {                    // fi -> chunks 0..7
            const float* pi = fi + (size_t)b * CIN * HW + hw;
#pragma unroll
            for (int d = 0; d < 8; ++d) {
                int c = cg * 16 + 2 * d;
                tile[p * TSX + cg * 8 + d] =
                    pack2(pi[(size_t)c * HW], pi[(size_t)(c + 1) * HW]);
            }
            __syncthreads();
#pragma unroll
            for (int i = 0; i < 2; ++i) {   // 512 quads: 8 per row
                int gq = i * 256 + tid;
                int rl = gq >> 3, c4 = gq & 7;
                const unsigned* s = &tile[rl * TSX + c4 * 4];
                uint4 v = {s[0], s[1], s[2], s[3]};
                dst[rl * 24 + c4] = v;
            }
        } else {                            // fj(permuted)+flow+pad -> 8..23
            const float* pj = fj + (size_t)b * CIN * HW + hw;
#pragma unroll
            for (int d = 0; d < 8; ++d) {
                int c = cg * 16 + 2 * d;
                tile[p * TSX + cg * 8 + d] =
                    pack2(pj[(size_t)c * HW], pj[(size_t)(c + 1) * HW]);
            }
            if (cg == 0) {
                const float* pf = fl + (size_t)b * 2 * HW + hw;
                tile[p * TSX + 32] = pack2(pf[0], pf[HW]);
            }
            __syncthreads();
#pragma unroll
            for (int i = 0; i < 4; ++i) {   // 1024 quads: 16 per row (8..23)
                int gq = i * 256 + tid;
                int rl = gq >> 4, c4 = gq & 15;
                uint4 v = {0u, 0u, 0u, 0u};
                if (c4 < 8) {
                    const unsigned* s = &tile[rl * TSX + c4 * 4];
                    v.x = s[0]; v.y = s[1]; v.z = s[2]; v.w = s[3];
                } else if (c4 == 8) {
                    v.x = tile[rl * TSX + 32];
                }
                int pc4 = (c4 < 8) ? ((c4 & 3) * 2 + (c4 >> 2)) : c4;  // permute
                dst[rl * 24 + 8 + pc4] = v;
            }
        }
    } else if (blk < PXB2 + PWBLK) {
        int e = (blk - PXB2) * 256 + threadIdx.x;
        if (e < NA) {                       // wa2f, fragment-dense
            int t  = e / 5120;
            int r1 = e - t * 5120;
            int ks = r1 >> 10;
            int r2 = r1 & 1023;
            int nt = r2 >> 9;
            int l9 = r2 & 511;
            int l  = l9 >> 3, ee = l9 & 7;
            int m  = l & 15, g = l >> 4;
            int oc = nt * 16 + m;
            int ch = ks * 32 + g * 8 + ee;
            float v = 0.0f;
            if (oc < 27 && ch < 130) {
                if (oc < 18) v = w_off[((size_t)oc * 130 + ch) * 9 + t];
                else         v = w_mod[((size_t)(oc - 18) * 130 + ch) * 9 + t];
            }
            wa2f[e] = f2bf(v);
        } else {
            int e2 = e - NA;
            if (e2 < NW) {                  // wb2f, fragment-dense
                int k  = e2 >> 12;
                int r1 = e2 & 4095;
                int ks = r1 >> 11;
                int r2 = r1 & 2047;
                int nt = r2 >> 9;
                int l9 = r2 & 511;
                int l  = l9 >> 3, ee = l9 & 7;
                int m  = l & 15, g = l >> 4;
                int o  = nt * 16 + m;
                int c  = ks * 32 + g * 8 + ee;
                wb2f[e2] = f2bf(w_reg[((size_t)o * 64 + c) * 9 + k]);
            }
        }
    } else {
        if (threadIdx.x < 24) {             // zero row, 24 dwordx4
            uint4 z = {0u, 0u, 0u, 0u};
            ((uint4*)(xt + (size_t)ZROW * C2B))[threadIdx.x] = z;
        }
    }
}

// ---------------------------------------------------------------------------
// Fused conv + deform, 4-way K-split, 1 strip/block. R14:
//  - Phase-1 A-data comes from an LDS-staged 3x18-row patch (staged once per
//    block with dense coalesced loads; rows contiguous along x). A-fragment
//    reads become conflict-clean ds_read_b128. Kills ~60 scattered wave-loads
//    per block.
//  - Phase-2 gathers use the permuted fj layout: each lane's two K-chunks are
//    at +0/+16B (fewer line splits); gather lines are L1-warm from staging.
// ---------------------------------------------------------------------------
__global__ __launch_bounds__(256, 2) void fused_kernel(
    const unsigned short* __restrict__ xt,
    const unsigned short* __restrict__ wa2f,
    const unsigned short* __restrict__ wb2f,
    const float* __restrict__ b_off, const float* __restrict__ b_mod,
    float* __restrict__ out)
{
    __shared__ __align__(16) uint4 patch4[20 * PR];   // 17.6 KB conv patch
    __shared__ float lraw[16 * 28];                   // 1.8 KB offsets/mods
    __shared__ __align__(16) float red[4][64 * RS];   // 20.5 KB partials

    int l = threadIdx.x & 63;
    int wid = __builtin_amdgcn_readfirstlane(threadIdx.x >> 6);
    int m = l & 15, g = l >> 4;
    int strip = (blockIdx.x & 7) * BPX3 + (blockIdx.x >> 3);  // XCD-contiguous
    int b = strip / (HW / 16);              // wave-uniform
    int hw0 = (strip - b * (HW / 16)) * 16;
    int hw = hw0 + m;
    int x = hw % WW, y = hw / WW;
    int y0b = hw0 / WW, x0b = hw0 - y0b * WW;   // strip base (x0b mult of 16)
    int t0 = wid * 2;
    int ntap = (wid == 3) ? 3 : 2;          // wave-uniform tap count

    // ---- Stage the 3x18-row patch (all 9 taps' A-data), dense loads ----
#pragma unroll
    for (int i = 0; i < 5; ++i) {
        int item = i * 256 + threadIdx.x;   // (run,row18,c8) row-major
        if (item < 1080) {
            int run = item / 360;
            int rem = item - run * 360;
            int r18 = rem / 20;
            int c8  = rem - r18 * 20;
            int yy = y0b + run - 1;
            int xx = x0b - 1 + r18;
            bool ok = ((unsigned)yy < HH) && ((unsigned)xx < WW);
            uint4 v = {0u, 0u, 0u, 0u};
            if (ok)
                v = ((const uint4*)(xt + (size_t)(b * HW + yy * WW + xx) * C2B))[c8];
            patch4[c8 * PR + run * 18 + r18] = v;
        }
    }
    __syncthreads();                        // barrier S

    // ---- Phase 1: conv partials over my taps (A from LDS) ----
    v4f acc0 = {0.f, 0.f, 0.f, 0.f};
    v4f acc1 = {0.f, 0.f, 0.f, 0.f};
#pragma unroll
    for (int ti = 0; ti < 3; ++ti) {
        if (ti < ntap) {
            int t = t0 + ti;
            int r = (t / 3) * 18 + (t % 3) + m;
#pragma unroll
            for (int ks = 0; ks < 5; ++ks) {
                // chunk remap (fj region permuted): {g, 4+g, 8+2g, 9+2g, 16+g}
                int c8 = (ks == 0) ? g : (ks == 1) ? 4 + g
                       : (ks == 2) ? 8 + 2 * g : (ks == 3) ? 9 + 2 * g : 16 + g;
                v8s a = *(const v8s*)&patch4[c8 * PR + r];
                const unsigned short* wp =
                    wa2f + ((size_t)((t * 5 + ks) * 2)) * 512 + l * 8;
                v8s b0 = *(const v8s*)(wp);
                v8s b1 = *(const v8s*)(wp + 512);
                acc0 = __builtin_amdgcn_mfma_f32_16x16x32_bf16(a, b0, acc0, 0, 0, 0);
                acc1 = __builtin_amdgcn_mfma_f32_16x16x32_bf16(a, b1, acc1, 0, 0, 0);
            }
        }
    }

    if (wid != 0) {                         // publish partials
        float* rb = &red[wid][l * RS];
        *(v4f*)(rb + 0) = acc0;
        *(v4f*)(rb + 4) = acc1;
    }
    __syncthreads();                        // barrier A
    if (wid == 0) {                         // reduce + epilogue -> lraw
#pragma unroll
        for (int sw = 1; sw < 4; ++sw) {
            const float* rb = &red[sw][l * RS];
            acc0 += *(const v4f*)(rb + 0);
            acc1 += *(const v4f*)(rb + 4);
        }
        float v0[4] = {acc0.x, acc0.y, acc0.z, acc0.w};
        float v1[4] = {acc1.x, acc1.y, acc1.z, acc1.w};
        float bo0 = b_off[m];
        int oc1 = 16 + m;
#pragma unroll
        for (int r = 0; r < 4; ++r)
            lraw[(g * 4 + r) * 28 + m] = v0[r] + bo0;
        if (oc1 < 18) {
            float bo1 = b_off[oc1];
#pragma unroll
            for (int r = 0; r < 4; ++r)
                lraw[(g * 4 + r) * 28 + oc1] = v1[r] + bo1;
        } else if (oc1 < 27) {
            float bm = b_mod[oc1 - 18];
#pragma unroll
            for (int r = 0; r < 4; ++r)
                lraw[(g * 4 + r) * 28 + oc1] =
                    2.0f / (1.0f + expf(-(v1[r] + bm)));
        }
    }
    __syncthreads();                        // barrier B

    // ---- Phase 2: compute all tap weights/addrs, issue ALL gathers ----
    float cw[3][4];
    uint4 gbuf[3][8];                       // [tap][ks*4+corner]
#pragma unroll
    for (int ti = 0; ti < 3; ++ti) {
        if (ti < ntap) {
            int k = t0 + ti;
            int ky = k / 3, kx = k - 3 * ky;
            float dy = lraw[m * 28 + 2 * k];
            float dx = lraw[m * 28 + 2 * k + 1];
            float mm = lraw[m * 28 + 18 + k];

            float py = (float)(y - 1 + ky) + dy;
            float px = (float)(x - 1 + kx) + dx;
            float fy = floorf(py), fx = floorf(px);
            int   y0 = (int)fy,    x0 = (int)fx;
            float wy = py - fy,    wx = px - fx;
            int   y1 = y0 + 1,     x1 = x0 + 1;

            bool y0v = (y0 >= 0) && (y0 < HH);
            bool y1v = (y1 >= 0) && (y1 < HH);
            bool x0v = (x0 >= 0) && (x0 < WW);
            bool x1v = (x1 >= 0) && (x1 < WW);

            cw[ti][0] = (1.f - wy) * (1.f - wx) * ((y0v && x0v) ? mm : 0.f);
            cw[ti][1] = (1.f - wy) * wx         * ((y0v && x1v) ? mm : 0.f);
            cw[ti][2] = wy * (1.f - wx)         * ((y1v && x0v) ? mm : 0.f);
            cw[ti][3] = wy * wx                 * ((y1v && x1v) ? mm : 0.f);

            int y0c = min(max(y0, 0), HH - 1), y1c = min(max(y1, 0), HH - 1);
            int x0c = min(max(x0, 0), WW - 1), x1c = min(max(x1, 0), WW - 1);
            int rb = b * HW;
            // permuted fj: lane's two K-chunks adjacent at +0 / +8 shorts
            const unsigned short* r00 = xt + (size_t)(rb + y0c * WW + x0c) * C2B + 64 + g * 16;
            const unsigned short* r01 = xt + (size_t)(rb + y0c * WW + x1c) * C2B + 64 + g * 16;
            const unsigned short* r10 = xt + (size_t)(rb + y1c * WW + x0c) * C2B + 64 + g * 16;
            const unsigned short* r11 = xt + (size_t)(rb + y1c * WW + x1c) * C2B + 64 + g * 16;
#pragma unroll
            for (int ks = 0; ks < 2; ++ks) {
                gbuf[ti][ks * 4 + 0] = *(const uint4*)(r00 + ks * 8);
                gbuf[ti][ks * 4 + 1] = *(const uint4*)(r01 + ks * 8);
                gbuf[ti][ks * 4 + 2] = *(const uint4*)(r10 + ks * 8);
                gbuf[ti][ks * 4 + 3] = *(const uint4*)(r11 + ks * 8);
            }
        }
    }
    __builtin_amdgcn_sched_barrier(0);      // keep gathers batched in flight

    v4f acc[4];
#pragma unroll
    for (int nt = 0; nt < 4; ++nt) acc[nt] = (v4f){0.f, 0.f, 0.f, 0.f};

#pragma unroll
    for (int ti = 0; ti < 3; ++ti) {
        if (ti < ntap) {
            int k = t0 + ti;
            float w00 = cw[ti][0], w01 = cw[ti][1];
            float w10 = cw[ti][2], w11 = cw[ti][3];
            v8s afrag[2];
#pragma unroll
            for (int ks = 0; ks < 2; ++ks) {
                uint4 u00 = gbuf[ti][ks * 4 + 0];
                uint4 u01 = gbuf[ti][ks * 4 + 1];
                uint4 u10 = gbuf[ti][ks * 4 + 2];
                uint4 u11 = gbuf[ti][ks * 4 + 3];
                uint4 ov;
                ov.x = bil2(u00.x, u01.x, u10.x, u11.x, w00, w01, w10, w11);
                ov.y = bil2(u00.y, u01.y, u10.y, u11.y, w00, w01, w10, w11);
                ov.z = bil2(u00.z, u01.z, u10.z, u11.z, w00, w01, w10, w11);
                ov.w = bil2(u00.w, u01.w, u10.w, u11.w, w00, w01, w10, w11);
                afrag[ks] = __builtin_bit_cast(v8s, ov);
            }
#pragma unroll
            for (int nt = 0; nt < 4; ++nt) {
#pragma unroll
                for (int ks = 0; ks < 2; ++ks) {
                    const unsigned short* wp =
                        wb2f + ((size_t)((k * 2 + ks) * 4 + nt)) * 512 + l * 8;
                    v8s bb = *(const v8s*)wp;
                    acc[nt] = __builtin_amdgcn_mfma_f32_16x16x32_bf16(
                        afrag[ks], bb, acc[nt], 0, 0, 0);
                }
            }
        }
    }

    {                                       // publish all 16 partials
        float* rb = &red[wid][l * RS];
        *(v4f*)(rb + 0)  = acc[0];
        *(v4f*)(rb + 4)  = acc[1];
        *(v4f*)(rb + 8)  = acc[2];
        *(v4f*)(rb + 12) = acc[3];
    }
    __syncthreads();                        // barrier C
    {                                       // wave w reduces + stores n-tile w
        v4f s = {0.f, 0.f, 0.f, 0.f};
#pragma unroll
        for (int sw = 0; sw < 4; ++sw)
            s += *(const v4f*)(&red[sw][l * RS + wid * 4]);
        float* op = out + ((size_t)(b * COUT + wid * 16 + m)) * HW + hw0 + g * 4;
        *(v4f*)op = s;
    }
}

extern "C" void kernel_launch(void* const* d_in, const int* in_sizes, int n_in,
                              void* d_out, int out_size, void* d_ws, size_t ws_size,
                              hipStream_t stream)
{
    const float* frame_i = (const float*)d_in[0];
    const float* frame_j = (const float*)d_in[1];
    const float* flow_ij = (const float*)d_in[2];
    const float* w_off   = (const float*)d_in[3];
    const float* b_off   = (const float*)d_in[4];
    const float* w_mod   = (const float*)d_in[5];
    const float* b_mod   = (const float*)d_in[6];
    const float* w_reg   = (const float*)d_in[7];
    float* out = (float*)d_out;

    // workspace: Xt bf16 [NROW+1][192] | Wa2f | Wb2f  (~14.3 MB)
    unsigned short* xt   = (unsigned short*)d_ws;
    unsigned short* wa2f = xt + (size_t)(NROW + 1) * C2B;
    unsigned short* wb2f = wa2f + NA;

    prep_kernel<<<PXB2 + PWBLK + 1, 256, 0, stream>>>(
        frame_i, frame_j, flow_ij, w_off, w_mod, w_reg, xt, wa2f, wb2f);

    fused_kernel<<<NSTRIP, 256, 0, stream>>>(
        xt, wa2f, wb2f, b_off, b_mod, out);
}